// Round 1
// 2296.980 us; speedup vs baseline: 1.1380x; 1.1380x over previous
//
#include <hip/hip_runtime.h>
#include <hip/hip_bf16.h>

// ---------------------------------------------------------------------------
// VQ-VAE pose: fused fp32 pipeline. Round 7:
//  - vq_k rewritten as tiled GEMM-argmin (was spilling z[64] to scratch:
//    VGPR=44, WRITE_SIZE 61.7MB vs 33.5MB legit, VALUBusy 26%).
//    New: 128 rows x 64-code chunks, 8x4 acc/thread, shfl_xor argmin reduce,
//    coalesced gather + straight-through write + diff. Uses Emb (d-major,
//    K-major for GEMM) directly; Et (code-major) kept for the gather.
// ---------------------------------------------------------------------------

#define NTOT 131072            // B*T
#define EDIM 64
#define NEMB 512

// ---------------- dtype detection (fp32 vs bf16) ---------------------------
__global__ void detect_k(const void* __restrict__ x, int* __restrict__ flag,
                         float* __restrict__ acc)
{
    __shared__ int s_bad;
    if (threadIdx.x == 0) s_bad = 0;
    __syncthreads();
    const unsigned short* u = (const unsigned short*)x;
    int bad = 0;
    for (int i = threadIdx.x; i < 2048; i += 256) {
        unsigned short h = u[i];
        int ex = (h >> 7) & 0xFF;
        if (h != 0 && (ex < 100 || ex > 140)) bad++;
    }
    atomicAdd(&s_bad, bad);
    __syncthreads();
    if (threadIdx.x == 0) { *flag = (s_bad > 256) ? 1 : 0; *acc = 0.f; }
}

// -------- convert weights to fp32; 2-D weights transposed to K-major -------
struct WTbl { const void* p[31]; int off[31]; int n[31]; int Kd[31]; };

__global__ void convw_k(WTbl t, float* __restrict__ dst, const int* __restrict__ flag)
{
    const bool f32 = (*flag != 0);
    const int ti = blockIdx.x;
    const void* src = t.p[ti];
    float* d = dst + t.off[ti];
    const int n = t.n[ti];
    const int K = t.Kd[ti];
    if (K == 0) {
        for (int i = threadIdx.x; i < n; i += 256)
            d[i] = f32 ? ((const float*)src)[i]
                       : __bfloat162float(((const __hip_bfloat16*)src)[i]);
    } else {
        const int O = n / K;
        for (int j = threadIdx.x; j < n; j += 256) {
            int k = j / O, o = j - k * O;           // dst[k][o] = src[o][k]
            int si = o * K + k;
            d[j] = f32 ? ((const float*)src)[si]
                       : __bfloat162float(((const __hip_bfloat16*)src)[si]);
        }
    }
}

// ---------------- fused enc0+enc1: x[165] -> relu128 -> relu256 ------------
__global__ __launch_bounds__(256)
void enc01_k(const void* __restrict__ X,
             const float* __restrict__ W0t, const float* __restrict__ B0,  // [165][128],[128]
             const float* __restrict__ W1t, const float* __restrict__ B1,  // [128][256],[256]
             float* __restrict__ Y, const int* __restrict__ dtf)
{
    __shared__ float Xs[32][64];     // k-major chunk: conflict-free lane reads
    __shared__ float H1[64][131];    // 128 cols + 3 pad (stride 131 -> 2-way, free)
    const bool f32d = (*dtf != 0);
    const int tid = threadIdx.x;
    const int r0  = blockIdx.x * 64;
    const int r   = tid & 63;
    const int w   = __builtin_amdgcn_readfirstlane(tid >> 6);   // wave id 0..3

    float acc[32] = {};
    for (int kc = 0; kc < 6; ++kc) {             // 6*32 = 192 >= 165
        const int k0 = kc * 32;
        #pragma unroll
        for (int it = 0; it < 8; ++it) {
            int e = tid + it * 256;              // 2048 = 64 rows x 32 k
            int kk = e & 31, m = e >> 5;
            int kg = k0 + kk;
            float v = 0.f;
            if (kg < 165) {
                size_t idx = (size_t)(r0 + m) * 165 + kg;
                v = f32d ? ((const float*)X)[idx]
                         : __bfloat162float(((const __hip_bfloat16*)X)[idx]);
            }
            Xs[kk][m] = v;
        }
        __syncthreads();
        #pragma unroll
        for (int kk = 0; kk < 32; ++kk) {
            float a = Xs[kk][r];
            const float* wp = W0t + (size_t)min(k0 + kk, 164) * 128 + w * 32;
            #pragma unroll
            for (int j = 0; j < 32; ++j)
                acc[j] = fmaf(a, wp[j], acc[j]);
        }
        __syncthreads();
    }
    #pragma unroll
    for (int j = 0; j < 32; ++j)
        H1[r][w * 32 + j] = fmaxf(acc[j] + B0[w * 32 + j], 0.f);
    __syncthreads();

    // layer 2: K=128 -> 256 cols (4 chunks of 16 per wave), relu, store
    #pragma unroll
    for (int c = 0; c < 4; ++c) {
        const int col0 = w * 64 + c * 16;
        float a2[16] = {};
        for (int k = 0; k < 128; ++k) {
            float tv = H1[r][k];
            const float* wp = W1t + (size_t)k * 256 + col0;
            #pragma unroll
            for (int j = 0; j < 16; ++j)
                a2[j] = fmaf(tv, wp[j], a2[j]);
        }
        float* out = Y + (size_t)(r0 + r) * 256 + col0;
        #pragma unroll
        for (int j = 0; j < 16; ++j)
            out[j] = fmaxf(a2[j] + B1[col0 + j], 0.f);
    }
}

// ---------------- fused resblock: h += W1 @ relu(W0 @ relu(h)) -------------
// In-place on H (each block owns its 64 rows; residual read is L2-hot).
__global__ __launch_bounds__(256)
void res_k(float* __restrict__ H,
           const float* __restrict__ W0t, const float* __restrict__ B0,  // [256][32],[32]
           const float* __restrict__ W1t, const float* __restrict__ B1)  // [32][256],[256]
{
    __shared__ float Hs[32][64];     // k-major chunk of relu(h)
    __shared__ float T1[64][33];     // mid activations (stride 33 -> free)
    const int tid = threadIdx.x;
    const int r0  = blockIdx.x * 64;
    const int r   = tid & 63;
    const int w   = __builtin_amdgcn_readfirstlane(tid >> 6);

    float acc[8] = {};
    for (int kc = 0; kc < 8; ++kc) {             // K=256
        const int k0 = kc * 32;
        #pragma unroll
        for (int it = 0; it < 8; ++it) {
            int e = tid + it * 256;
            int kk = e & 31, m = e >> 5;
            Hs[kk][m] = fmaxf(H[(size_t)(r0 + m) * 256 + k0 + kk], 0.f);
        }
        __syncthreads();
        #pragma unroll
        for (int kk = 0; kk < 32; ++kk) {
            float a = Hs[kk][r];
            const float* wp = W0t + (size_t)(k0 + kk) * 32 + w * 8;
            #pragma unroll
            for (int j = 0; j < 8; ++j)
                acc[j] = fmaf(a, wp[j], acc[j]);
        }
        __syncthreads();
    }
    #pragma unroll
    for (int j = 0; j < 8; ++j)
        T1[r][w * 8 + j] = fmaxf(acc[j] + B0[w * 8 + j], 0.f);
    __syncthreads();

    // mm2: K=32 -> 256 cols; add residual (in-place) + bias
    #pragma unroll
    for (int c = 0; c < 4; ++c) {
        const int col0 = w * 64 + c * 16;
        float a2[16] = {};
        #pragma unroll
        for (int k = 0; k < 32; ++k) {
            float tv = T1[r][k];
            const float* wp = W1t + (size_t)k * 256 + col0;
            #pragma unroll
            for (int j = 0; j < 16; ++j)
                a2[j] = fmaf(tv, wp[j], a2[j]);
        }
        float* out = H + (size_t)(r0 + r) * 256 + col0;
        #pragma unroll
        for (int j = 0; j < 16; ++j)
            out[j] = out[j] + a2[j] + B1[col0 + j];
    }
}

// ---------------- standalone GEMM (fp32 X, K-major W, swizzled grid) -------
// grid = (ceil(O/64), M/128): col-block fastest -> concurrent blocks share X.
template <bool PRE_RELU, bool POST_RELU, int YM>
__global__ __launch_bounds__(256)
void gemm_k(const float* __restrict__ X, const float* __restrict__ Wt,
            const float* __restrict__ Bv, void* __restrict__ Y,
            int K, int O, const int* __restrict__ dtf)
{
    __shared__ float Xs[32][132];
    __shared__ float Ws[32][68];

    const bool f32d = (YM == 1) ? (*dtf != 0) : false;
    const int tid = threadIdx.x;
    const int tx  = tid & 15;
    const int ty  = tid >> 4;
    const int o0  = blockIdx.x * 64;
    const int m0  = blockIdx.y * 128;

    float acc[8][4] = {};
    const int KC = K >> 5;                       // K multiple of 32
    for (int kc = 0; kc < KC; ++kc) {
        const int k0 = kc << 5;
        #pragma unroll
        for (int it = 0; it < 4; ++it) {         // X: 128 x 32 as float4
            int idx = tid + it * 256;
            int kq = idx & 7, m = idx >> 3;
            float4 v = *(const float4*)(X + (size_t)(m0 + m) * K + k0 + kq * 4);
            if (PRE_RELU) {
                v.x = fmaxf(v.x, 0.f); v.y = fmaxf(v.y, 0.f);
                v.z = fmaxf(v.z, 0.f); v.w = fmaxf(v.w, 0.f);
            }
            Xs[kq * 4 + 0][m] = v.x; Xs[kq * 4 + 1][m] = v.y;
            Xs[kq * 4 + 2][m] = v.z; Xs[kq * 4 + 3][m] = v.w;
        }
        if ((O & 3) == 0) {                      // W: 32 x 64, K-major direct
            #pragma unroll
            for (int it = 0; it < 2; ++it) {
                int idx = tid + it * 256;
                int oq = idx & 15, kk = idx >> 4;
                float4 v = make_float4(0.f, 0.f, 0.f, 0.f);
                if (o0 + oq * 4 < O)
                    v = *(const float4*)(Wt + (size_t)(k0 + kk) * O + o0 + oq * 4);
                *(float4*)&Ws[kk][oq * 4] = v;
            }
        } else {
            #pragma unroll
            for (int it = 0; it < 8; ++it) {
                int e = tid + it * 256;
                int kk = e & 31, o = e >> 5;
                int og = o0 + o;
                Ws[kk][o] = (og < O) ? Wt[(size_t)(k0 + kk) * O + og] : 0.f;
            }
        }
        __syncthreads();
        #pragma unroll
        for (int kk = 0; kk < 32; ++kk) {
            float a[8], b[4];
            *(float4*)&a[0] = *(const float4*)&Xs[kk][ty * 8];
            *(float4*)&a[4] = *(const float4*)&Xs[kk][ty * 8 + 4];
            *(float4*)&b[0] = *(const float4*)&Ws[kk][tx * 4];
            #pragma unroll
            for (int i = 0; i < 8; ++i)
                #pragma unroll
                for (int j = 0; j < 4; ++j)
                    acc[i][j] = fmaf(a[i], b[j], acc[i][j]);
        }
        __syncthreads();
    }

    if (YM == 0 && (O & 63) == 0) {
        const int c0 = o0 + tx * 4;
        float4 bb = *(const float4*)(Bv + c0);
        #pragma unroll
        for (int i = 0; i < 8; ++i) {
            int r = m0 + ty * 8 + i;
            float4 v;
            v.x = acc[i][0] + bb.x; v.y = acc[i][1] + bb.y;
            v.z = acc[i][2] + bb.z; v.w = acc[i][3] + bb.w;
            if (POST_RELU) {
                v.x = fmaxf(v.x, 0.f); v.y = fmaxf(v.y, 0.f);
                v.z = fmaxf(v.z, 0.f); v.w = fmaxf(v.w, 0.f);
            }
            *(float4*)((float*)Y + (size_t)r * O + c0) = v;
        }
    } else {
        #pragma unroll
        for (int j = 0; j < 4; ++j) {
            int c = o0 + tx * 4 + j;
            if (c >= O) continue;
            float bb = Bv[c];
            #pragma unroll
            for (int i = 0; i < 8; ++i) {
                int r = m0 + ty * 8 + i;
                float v = acc[i][j] + bb;
                if (POST_RELU) v = fmaxf(v, 0.f);
                size_t yi = (size_t)r * O + c;
                if (YM == 0)   ((float*)Y)[yi] = v;
                else if (f32d) ((float*)Y)[yi] = v;
                else           ((__hip_bfloat16*)Y)[yi] = __float2bfloat16(v);
            }
        }
    }
}

// ---------------- codebook prep --------------------------------------------
__global__ void prep_k(const float* __restrict__ E, float* __restrict__ Et)
{
    int idx = blockIdx.x * 256 + threadIdx.x;   // E is [64][512]
    Et[(idx & 511) * EDIM + (idx >> 9)] = E[idx];
}

__global__ void e2_k(const float* __restrict__ Et, float* __restrict__ e2)
{
    int e = blockIdx.x * 256 + threadIdx.x;
    float s = 0.f;
    #pragma unroll
    for (int d = 0; d < EDIM; ++d) { float v = Et[e * EDIM + d]; s = fmaf(v, v, s); }
    e2[e] = s;
}

// ---------------- VQ as tiled GEMM-argmin ----------------------------------
// Block: 128 rows x all 512 codes (8 chunks of 64). Ed is the converted embed
// in its native [64][512] d-major layout == K-major B operand. Et (code-major)
// only used for the coalesced gather of winning rows.
// Per thread: 8 rows (ty) x 4 codes (tx) acc; running (best,idx) per row;
// shfl_xor reduce over the 16 lanes sharing a row; straight-through write.
__global__ __launch_bounds__(256)
void vq_k(float* __restrict__ Zq, const float* __restrict__ Ed,
          const float* __restrict__ Et, const float* __restrict__ e2,
          float* __restrict__ acc)
{
    __shared__ float Zs[64][132];    // [d][row], 128 rows + pad
    __shared__ float Es[64][68];     // [d][code] chunk of 64 codes

    const int tid = threadIdx.x;
    const int tx  = tid & 15;        // code group (4 codes)
    const int ty  = tid >> 4;        // row group (8 rows)
    const int r0  = blockIdx.x * 128;

    // stage Z tile k-major
    #pragma unroll
    for (int it = 0; it < 8; ++it) {
        int idx = tid + it * 256;                // 128 rows x 16 float4
        int dq = idx & 15, m = idx >> 4;
        float4 v = *(const float4*)(Zq + (size_t)(r0 + m) * 64 + dq * 4);
        Zs[dq * 4 + 0][m] = v.x; Zs[dq * 4 + 1][m] = v.y;
        Zs[dq * 4 + 2][m] = v.z; Zs[dq * 4 + 3][m] = v.w;
    }

    float best[8];
    int   bi[8];
    #pragma unroll
    for (int i = 0; i < 8; ++i) { best[i] = 3.4e38f; bi[i] = 0; }

    for (int cc = 0; cc < 8; ++cc) {
        const int c0 = cc * 64;
        // stage E chunk: Ed[kk][c0+..] straight float4 copy (already K-major)
        #pragma unroll
        for (int it = 0; it < 4; ++it) {
            int idx = tid + it * 256;            // 64 k x 16 float4
            int oq = idx & 15, kk = idx >> 4;
            *(float4*)&Es[kk][oq * 4] =
                *(const float4*)(Ed + (size_t)kk * NEMB + c0 + oq * 4);
        }
        float4 e2v = *(const float4*)(e2 + c0 + tx * 4);  // hidden under k-loop
        __syncthreads();

        float a4[8][4] = {};
        #pragma unroll 8
        for (int kk = 0; kk < 64; ++kk) {
            float a[8], b[4];
            *(float4*)&a[0] = *(const float4*)&Zs[kk][ty * 8];
            *(float4*)&a[4] = *(const float4*)&Zs[kk][ty * 8 + 4];
            *(float4*)&b[0] = *(const float4*)&Es[kk][tx * 4];
            #pragma unroll
            for (int i = 0; i < 8; ++i)
                #pragma unroll
                for (int j = 0; j < 4; ++j)
                    a4[i][j] = fmaf(a[i], b[j], a4[i][j]);
        }

        const float e2a[4] = {e2v.x, e2v.y, e2v.z, e2v.w};
        #pragma unroll
        for (int j = 0; j < 4; ++j) {
            const int code = c0 + tx * 4 + j;    // visited in increasing order
            #pragma unroll
            for (int i = 0; i < 8; ++i) {
                float s = fmaf(-2.f, a4[i][j], e2a[j]);
                if (s < best[i]) { best[i] = s; bi[i] = code; }  // strict <: first-min
            }
        }
        __syncthreads();
    }

    // argmin reduce over the 16 lanes (tx = lane bits 0..3) sharing each row;
    // tie-break on smaller index to match jnp.argmin semantics.
    #pragma unroll
    for (int i = 0; i < 8; ++i) {
        #pragma unroll
        for (int m = 1; m < 16; m <<= 1) {
            float ob = __shfl_xor(best[i], m);
            int   oi = __shfl_xor(bi[i], m);
            if (ob < best[i] || (ob == best[i] && oi < bi[i])) {
                best[i] = ob; bi[i] = oi;
            }
        }
    }

    // gather winner rows (coalesced: 16 lanes x float4 = one 64-float row),
    // straight-through write in place, accumulate commitment diff.
    float ds = 0.f;
    #pragma unroll
    for (int i = 0; i < 8; ++i) {
        const int row = r0 + ty * 8 + i;
        float4 qv = *(const float4*)(Et + (size_t)bi[i] * 64 + tx * 4);
        float* zp = Zq + (size_t)row * 64 + tx * 4;
        float4 zv = *(const float4*)zp;          // L2-hot re-read, avoids LDS conflicts
        float t;
        t = qv.x - zv.x; ds = fmaf(t, t, ds);
        t = qv.y - zv.y; ds = fmaf(t, t, ds);
        t = qv.z - zv.z; ds = fmaf(t, t, ds);
        t = qv.w - zv.w; ds = fmaf(t, t, ds);
        *(float4*)zp = qv;
    }
    #pragma unroll
    for (int off = 32; off; off >>= 1) ds += __shfl_down(ds, off);
    if ((tid & 63) == 0) atomicAdd(acc, ds);
}

__global__ void diff_k(const float* __restrict__ acc, void* __restrict__ out,
                       size_t off, const int* __restrict__ dtf)
{
    if (threadIdx.x == 0) {
        float v = *acc * (1.0f / 8388608.0f);
        if (*dtf) ((float*)out)[off] = v;
        else      ((__hip_bfloat16*)out)[off] = __float2bfloat16(v);
    }
}

// ---------------------------------------------------------------------------
extern "C" void kernel_launch(void* const* d_in, const int* in_sizes, int n_in,
                              void* d_out, int out_size, void* d_ws, size_t ws_size,
                              hipStream_t stream)
{
    const size_t MB = 1048576;
    char* ws = (char*)d_ws;
    float* Zq  = (float*)ws;                                  // N x 64
    float* A1  = (float*)(ws + 32 * MB);                      // N x 256
    float* A2  = (float*)(ws + 32 * MB + 128 * MB);           // N x 256
    float* Wf  = (float*)(ws + 288 * MB);                     // fp32 weights
    float* Et  = (float*)(ws + 288 * MB + 1310720);           // 512 x 64
    float* e2  = Et + NEMB * EDIM;
    float* acc = e2 + NEMB;
    int*   dtf = (int*)(acc + 1);

    // weight table (K-major transpose for 2-D weights)
    static const int KDIM[32] = {0, 165,0, 128,0, 256,0, 256,0, 32,0, 256,0, 32,0,
                                 256,0, 0, 64,0, 256,0, 32,0, 256,0, 32,0, 256,0, 128,0};
    WTbl t;
    int off[32];
    int cum = 0;
    for (int i = 1; i < 32; ++i) {
        t.p[i - 1]   = d_in[i];
        t.off[i - 1] = cum;
        t.n[i - 1]   = in_sizes[i];
        t.Kd[i - 1]  = KDIM[i];
        off[i] = cum;
        cum += in_sizes[i];
    }
    const float* W_ew0 = Wf + off[1],  *B_ew0 = Wf + off[2];
    const float* W_ew1 = Wf + off[3],  *B_ew1 = Wf + off[4];
    const float* W_ew2 = Wf + off[5],  *B_ew2 = Wf + off[6];
    const float* W_r0a = Wf + off[7],  *B_r0a = Wf + off[8];
    const float* W_r0b = Wf + off[9],  *B_r0b = Wf + off[10];
    const float* W_r1a = Wf + off[11], *B_r1a = Wf + off[12];
    const float* W_r1b = Wf + off[13], *B_r1b = Wf + off[14];
    const float* W_qc  = Wf + off[15], *B_qc  = Wf + off[16];
    const float* Emb   = Wf + off[17];
    const float* W_d0  = Wf + off[18], *B_d0  = Wf + off[19];
    const float* W_s0a = Wf + off[20], *B_s0a = Wf + off[21];
    const float* W_s0b = Wf + off[22], *B_s0b = Wf + off[23];
    const float* W_s1a = Wf + off[24], *B_s1a = Wf + off[25];
    const float* W_s1b = Wf + off[26], *B_s1b = Wf + off[27];
    const float* W_d1  = Wf + off[28], *B_d1  = Wf + off[29];
    const float* W_d2  = Wf + off[30], *B_d2  = Wf + off[31];

    dim3 blk(256);
    const int NB = NTOT / 64;          // 2048 row blocks for fused kernels
    auto g = [](int o) { return dim3((o + 63) / 64, NTOT / 128); };  // swizzled

    detect_k<<<1, blk, 0, stream>>>(d_in[0], dtf, acc);
    convw_k<<<31, blk, 0, stream>>>(t, Wf, dtf);
    prep_k<<<128, blk, 0, stream>>>(Emb, Et);
    e2_k<<<2, blk, 0, stream>>>(Et, e2);

    // ---- encoder ----
    enc01_k<<<NB, blk, 0, stream>>>(d_in[0], W_ew0, B_ew0, W_ew1, B_ew1, A1, dtf);
    gemm_k<false, false, 0><<<g(256), blk, 0, stream>>>(A1, W_ew2, B_ew2, A2, 256, 256, dtf);
    res_k<<<NB, blk, 0, stream>>>(A2, W_r0a, B_r0a, W_r0b, B_r0b);
    res_k<<<NB, blk, 0, stream>>>(A2, W_r1a, B_r1a, W_r1b, B_r1b);
    gemm_k<true, false, 0><<<g(64), blk, 0, stream>>>(A2, W_qc, B_qc, Zq, 256, 64, dtf);

    // ---- VQ (in place, GEMM-argmin) ----
    vq_k<<<NTOT / 128, blk, 0, stream>>>(Zq, Emb, Et, e2, acc);

    // ---- decoder ----
    gemm_k<false, false, 0><<<g(256), blk, 0, stream>>>(Zq, W_d0, B_d0, A1, 64, 256, dtf);
    res_k<<<NB, blk, 0, stream>>>(A1, W_s0a, B_s0a, W_s0b, B_s0b);
    res_k<<<NB, blk, 0, stream>>>(A1, W_s1a, B_s1a, W_s1b, B_s1b);
    gemm_k<true, true, 0><<<g(128), blk, 0, stream>>>(A1, W_d1, B_d1, A2, 256, 128, dtf);
    gemm_k<false, false, 1><<<g(165), blk, 0, stream>>>(A2, W_d2, B_d2, d_out, 128, 165, dtf);

    diff_k<<<1, 64, 0, stream>>>(acc, d_out, (size_t)NTOT * 165, dtf);
}

// Round 2
// 1782.109 us; speedup vs baseline: 1.4668x; 1.2889x over previous
//
#include <hip/hip_runtime.h>
#include <hip/hip_bf16.h>

// ---------------------------------------------------------------------------
// VQ-VAE pose: fused fp32 pipeline. Round 8:
//  - enc01_k restructured to per-lane micro-kernel (was: 32-way LDS bank
//    conflict on k-major staging [inner dim 64 -> all lanes same bank,
//    2.43e7 conflicts] + uncoalesced per-row scalar stores [WRITE 211MB vs
//    134 legit] + wave-uniform weight broadcast at 33% VALUBusy).
//    New: X tile staged once (linear, conflict-free), H1 in LDS, W0/W1
//    per-lane from L2, coalesced float4 epilogue, 2 barriers.
//  - res_k restructured likewise: raw H staged once in LDS (residual read
//    from LDS -> HBM traffic 3x -> 2x), micro-kernel mm1/mm2, coalesced
//    float4 in-place store, 2 barriers.
// ---------------------------------------------------------------------------

#define NTOT 131072            // B*T
#define EDIM 64
#define NEMB 512

// ---------------- dtype detection (fp32 vs bf16) ---------------------------
__global__ void detect_k(const void* __restrict__ x, int* __restrict__ flag,
                         float* __restrict__ acc)
{
    __shared__ int s_bad;
    if (threadIdx.x == 0) s_bad = 0;
    __syncthreads();
    const unsigned short* u = (const unsigned short*)x;
    int bad = 0;
    for (int i = threadIdx.x; i < 2048; i += 256) {
        unsigned short h = u[i];
        int ex = (h >> 7) & 0xFF;
        if (h != 0 && (ex < 100 || ex > 140)) bad++;
    }
    atomicAdd(&s_bad, bad);
    __syncthreads();
    if (threadIdx.x == 0) { *flag = (s_bad > 256) ? 1 : 0; *acc = 0.f; }
}

// -------- convert weights to fp32; 2-D weights transposed to K-major -------
struct WTbl { const void* p[31]; int off[31]; int n[31]; int Kd[31]; };

__global__ void convw_k(WTbl t, float* __restrict__ dst, const int* __restrict__ flag)
{
    const bool f32 = (*flag != 0);
    const int ti = blockIdx.x;
    const void* src = t.p[ti];
    float* d = dst + t.off[ti];
    const int n = t.n[ti];
    const int K = t.Kd[ti];
    if (K == 0) {
        for (int i = threadIdx.x; i < n; i += 256)
            d[i] = f32 ? ((const float*)src)[i]
                       : __bfloat162float(((const __hip_bfloat16*)src)[i]);
    } else {
        const int O = n / K;
        for (int j = threadIdx.x; j < n; j += 256) {
            int k = j / O, o = j - k * O;           // dst[k][o] = src[o][k]
            int si = o * K + k;
            d[j] = f32 ? ((const float*)src)[si]
                       : __bfloat162float(((const __hip_bfloat16*)src)[si]);
        }
    }
}

// ---------------- fused enc0+enc1: x[165] -> relu128 -> relu256 ------------
// Micro-kernel form: tx=tid&31 (4 cols), ty=tid>>5 (8 rows). X tile staged
// once (linear coalesced, conflict-free); W0/W1 read per-lane from L2
// (215 KB resident); H1 kept in LDS; coalesced float4 stores.
__global__ __launch_bounds__(256)
void enc01_k(const void* __restrict__ X,
             const float* __restrict__ W0t, const float* __restrict__ B0,  // [165][128],[128]
             const float* __restrict__ W1t, const float* __restrict__ B1,  // [128][256],[256]
             float* __restrict__ Y, const int* __restrict__ dtf)
{
    __shared__ float Xr[64][168];    // raw X tile, row-major (broadcast reads)
    __shared__ float H1[64][132];    // mid activations, row-major

    const bool f32d = (*dtf != 0);
    const int tid = threadIdx.x;
    const int tx  = tid & 31;        // col group (4 cols)
    const int ty  = tid >> 5;        // row group (8 rows)
    const int r0  = blockIdx.x * 64;

    // stage X tile: linear element index -> coalesced global, conflict-free LDS
    {
        const size_t base = (size_t)r0 * 165;
        for (int e = tid; e < 64 * 165; e += 256) {
            int m = e / 165, k = e - m * 165;
            float v = f32d ? ((const float*)X)[base + e]
                           : __bfloat162float(((const __hip_bfloat16*)X)[base + e]);
            Xr[m][k] = v;
        }
    }
    __syncthreads();

    // ---- layer 1: K=165, 128 cols; acc1[8][4] ----
    float acc1[8][4] = {};
    #pragma unroll 4
    for (int k = 0; k < 165; ++k) {
        float b[4];
        *(float4*)&b[0] = *(const float4*)(W0t + (size_t)k * 128 + tx * 4);
        float a[8];
        #pragma unroll
        for (int i = 0; i < 8; ++i) a[i] = Xr[ty * 8 + i][k];
        #pragma unroll
        for (int i = 0; i < 8; ++i)
            #pragma unroll
            for (int j = 0; j < 4; ++j)
                acc1[i][j] = fmaf(a[i], b[j], acc1[i][j]);
    }
    {
        float bb[4];
        *(float4*)&bb[0] = *(const float4*)(B0 + tx * 4);
        #pragma unroll
        for (int i = 0; i < 8; ++i) {
            float4 v;
            v.x = fmaxf(acc1[i][0] + bb[0], 0.f);
            v.y = fmaxf(acc1[i][1] + bb[1], 0.f);
            v.z = fmaxf(acc1[i][2] + bb[2], 0.f);
            v.w = fmaxf(acc1[i][3] + bb[3], 0.f);
            *(float4*)&H1[ty * 8 + i][tx * 4] = v;
        }
    }
    __syncthreads();

    // ---- layer 2: K=128, 256 cols (2 chunks of 128); acc2[2][8][4] ----
    float acc2[2][8][4] = {};
    #pragma unroll 4
    for (int k = 0; k < 128; ++k) {
        float b0[4], b1[4], a[8];
        *(float4*)&b0[0] = *(const float4*)(W1t + (size_t)k * 256 + tx * 4);
        *(float4*)&b1[0] = *(const float4*)(W1t + (size_t)k * 256 + 128 + tx * 4);
        #pragma unroll
        for (int i = 0; i < 8; ++i) a[i] = H1[ty * 8 + i][k];
        #pragma unroll
        for (int i = 0; i < 8; ++i)
            #pragma unroll
            for (int j = 0; j < 4; ++j) {
                acc2[0][i][j] = fmaf(a[i], b0[j], acc2[0][i][j]);
                acc2[1][i][j] = fmaf(a[i], b1[j], acc2[1][i][j]);
            }
    }
    {
        float bb0[4], bb1[4];
        *(float4*)&bb0[0] = *(const float4*)(B1 + tx * 4);
        *(float4*)&bb1[0] = *(const float4*)(B1 + 128 + tx * 4);
        #pragma unroll
        for (int i = 0; i < 8; ++i) {
            const size_t row = (size_t)(r0 + ty * 8 + i) * 256;
            float4 v0, v1;
            v0.x = fmaxf(acc2[0][i][0] + bb0[0], 0.f);
            v0.y = fmaxf(acc2[0][i][1] + bb0[1], 0.f);
            v0.z = fmaxf(acc2[0][i][2] + bb0[2], 0.f);
            v0.w = fmaxf(acc2[0][i][3] + bb0[3], 0.f);
            v1.x = fmaxf(acc2[1][i][0] + bb1[0], 0.f);
            v1.y = fmaxf(acc2[1][i][1] + bb1[1], 0.f);
            v1.z = fmaxf(acc2[1][i][2] + bb1[2], 0.f);
            v1.w = fmaxf(acc2[1][i][3] + bb1[3], 0.f);
            *(float4*)(Y + row + tx * 4)       = v0;
            *(float4*)(Y + row + 128 + tx * 4) = v1;
        }
    }
}

// ---------------- fused resblock: h += W1 @ relu(W0 @ relu(h)) -------------
// Raw H tile staged once in LDS (residual read comes from LDS, not HBM);
// mm1/mm2 micro-kernels with per-lane L2 weight reads; coalesced stores.
__global__ __launch_bounds__(256)
void res_k(float* __restrict__ H,
           const float* __restrict__ W0t, const float* __restrict__ B0,  // [256][32],[32]
           const float* __restrict__ W1t, const float* __restrict__ B1)  // [32][256],[256]
{
    __shared__ float Hr[64][260];    // raw H tile (pre-relu), row-major
    __shared__ float T1[32][68];     // mid activations, k-major [midcol][row]

    const int tid = threadIdx.x;
    const int r0  = blockIdx.x * 64;

    // stage raw H tile: coalesced float4
    #pragma unroll
    for (int it = 0; it < 16; ++it) {
        int idx = tid + it * 256;                // 64 rows x 64 float4
        int q = idx & 63, m = idx >> 6;
        float4 v = *(const float4*)(H + (size_t)(r0 + m) * 256 + q * 4);
        *(float4*)&Hr[m][q * 4] = v;
    }
    __syncthreads();

    // mm1: 64 rows x 32 cols, K=256; tx1=tid&7 (4 cols), ty1=tid>>3 (2 rows)
    const int tx1 = tid & 7;
    const int ty1 = tid >> 3;
    float acc1[2][4] = {};
    #pragma unroll 8
    for (int k = 0; k < 256; ++k) {
        float b[4];
        *(float4*)&b[0] = *(const float4*)(W0t + (size_t)k * 32 + tx1 * 4);
        float a0 = fmaxf(Hr[ty1 * 2][k], 0.f);
        float a1 = fmaxf(Hr[ty1 * 2 + 1][k], 0.f);
        #pragma unroll
        for (int j = 0; j < 4; ++j) {
            acc1[0][j] = fmaf(a0, b[j], acc1[0][j]);
            acc1[1][j] = fmaf(a1, b[j], acc1[1][j]);
        }
    }
    {
        float bb[4];
        *(float4*)&bb[0] = *(const float4*)(B0 + tx1 * 4);
        #pragma unroll
        for (int i = 0; i < 2; ++i)
            #pragma unroll
            for (int j = 0; j < 4; ++j)
                T1[tx1 * 4 + j][ty1 * 2 + i] = fmaxf(acc1[i][j] + bb[j], 0.f);
    }
    __syncthreads();

    // mm2: 64 rows x 256 cols, K=32; tx2=tid&31 (4 cols x2), ty2=tid>>5 (8 rows)
    const int tx2 = tid & 31;
    const int ty2 = tid >> 5;
    float acc2[2][8][4] = {};
    #pragma unroll 8
    for (int k = 0; k < 32; ++k) {
        float b0[4], b1[4], a[8];
        *(float4*)&b0[0] = *(const float4*)(W1t + (size_t)k * 256 + tx2 * 4);
        *(float4*)&b1[0] = *(const float4*)(W1t + (size_t)k * 256 + 128 + tx2 * 4);
        *(float4*)&a[0] = *(const float4*)&T1[k][ty2 * 8];
        *(float4*)&a[4] = *(const float4*)&T1[k][ty2 * 8 + 4];
        #pragma unroll
        for (int i = 0; i < 8; ++i)
            #pragma unroll
            for (int j = 0; j < 4; ++j) {
                acc2[0][i][j] = fmaf(a[i], b0[j], acc2[0][i][j]);
                acc2[1][i][j] = fmaf(a[i], b1[j], acc2[1][i][j]);
            }
    }
    {
        float bb0[4], bb1[4];
        *(float4*)&bb0[0] = *(const float4*)(B1 + tx2 * 4);
        *(float4*)&bb1[0] = *(const float4*)(B1 + 128 + tx2 * 4);
        #pragma unroll
        for (int i = 0; i < 8; ++i) {
            const int row = ty2 * 8 + i;
            const size_t gr = (size_t)(r0 + row) * 256;
            float4 h0 = *(const float4*)&Hr[row][tx2 * 4];
            float4 h1 = *(const float4*)&Hr[row][128 + tx2 * 4];
            float4 v0, v1;
            v0.x = h0.x + acc2[0][i][0] + bb0[0];
            v0.y = h0.y + acc2[0][i][1] + bb0[1];
            v0.z = h0.z + acc2[0][i][2] + bb0[2];
            v0.w = h0.w + acc2[0][i][3] + bb0[3];
            v1.x = h1.x + acc2[1][i][0] + bb1[0];
            v1.y = h1.y + acc2[1][i][1] + bb1[1];
            v1.z = h1.z + acc2[1][i][2] + bb1[2];
            v1.w = h1.w + acc2[1][i][3] + bb1[3];
            *(float4*)(H + gr + tx2 * 4)       = v0;
            *(float4*)(H + gr + 128 + tx2 * 4) = v1;
        }
    }
}

// ---------------- standalone GEMM (fp32 X, K-major W, swizzled grid) -------
// grid = (ceil(O/64), M/128): col-block fastest -> concurrent blocks share X.
template <bool PRE_RELU, bool POST_RELU, int YM>
__global__ __launch_bounds__(256)
void gemm_k(const float* __restrict__ X, const float* __restrict__ Wt,
            const float* __restrict__ Bv, void* __restrict__ Y,
            int K, int O, const int* __restrict__ dtf)
{
    __shared__ float Xs[32][132];
    __shared__ float Ws[32][68];

    const bool f32d = (YM == 1) ? (*dtf != 0) : false;
    const int tid = threadIdx.x;
    const int tx  = tid & 15;
    const int ty  = tid >> 4;
    const int o0  = blockIdx.x * 64;
    const int m0  = blockIdx.y * 128;

    float acc[8][4] = {};
    const int KC = K >> 5;                       // K multiple of 32
    for (int kc = 0; kc < KC; ++kc) {
        const int k0 = kc << 5;
        #pragma unroll
        for (int it = 0; it < 4; ++it) {         // X: 128 x 32 as float4
            int idx = tid + it * 256;
            int kq = idx & 7, m = idx >> 3;
            float4 v = *(const float4*)(X + (size_t)(m0 + m) * K + k0 + kq * 4);
            if (PRE_RELU) {
                v.x = fmaxf(v.x, 0.f); v.y = fmaxf(v.y, 0.f);
                v.z = fmaxf(v.z, 0.f); v.w = fmaxf(v.w, 0.f);
            }
            Xs[kq * 4 + 0][m] = v.x; Xs[kq * 4 + 1][m] = v.y;
            Xs[kq * 4 + 2][m] = v.z; Xs[kq * 4 + 3][m] = v.w;
        }
        if ((O & 3) == 0) {                      // W: 32 x 64, K-major direct
            #pragma unroll
            for (int it = 0; it < 2; ++it) {
                int idx = tid + it * 256;
                int oq = idx & 15, kk = idx >> 4;
                float4 v = make_float4(0.f, 0.f, 0.f, 0.f);
                if (o0 + oq * 4 < O)
                    v = *(const float4*)(Wt + (size_t)(k0 + kk) * O + o0 + oq * 4);
                *(float4*)&Ws[kk][oq * 4] = v;
            }
        } else {
            #pragma unroll
            for (int it = 0; it < 8; ++it) {
                int e = tid + it * 256;
                int kk = e & 31, o = e >> 5;
                int og = o0 + o;
                Ws[kk][o] = (og < O) ? Wt[(size_t)(k0 + kk) * O + og] : 0.f;
            }
        }
        __syncthreads();
        #pragma unroll
        for (int kk = 0; kk < 32; ++kk) {
            float a[8], b[4];
            *(float4*)&a[0] = *(const float4*)&Xs[kk][ty * 8];
            *(float4*)&a[4] = *(const float4*)&Xs[kk][ty * 8 + 4];
            *(float4*)&b[0] = *(const float4*)&Ws[kk][tx * 4];
            #pragma unroll
            for (int i = 0; i < 8; ++i)
                #pragma unroll
                for (int j = 0; j < 4; ++j)
                    acc[i][j] = fmaf(a[i], b[j], acc[i][j]);
        }
        __syncthreads();
    }

    if (YM == 0 && (O & 63) == 0) {
        const int c0 = o0 + tx * 4;
        float4 bb = *(const float4*)(Bv + c0);
        #pragma unroll
        for (int i = 0; i < 8; ++i) {
            int r = m0 + ty * 8 + i;
            float4 v;
            v.x = acc[i][0] + bb.x; v.y = acc[i][1] + bb.y;
            v.z = acc[i][2] + bb.z; v.w = acc[i][3] + bb.w;
            if (POST_RELU) {
                v.x = fmaxf(v.x, 0.f); v.y = fmaxf(v.y, 0.f);
                v.z = fmaxf(v.z, 0.f); v.w = fmaxf(v.w, 0.f);
            }
            *(float4*)((float*)Y + (size_t)r * O + c0) = v;
        }
    } else {
        #pragma unroll
        for (int j = 0; j < 4; ++j) {
            int c = o0 + tx * 4 + j;
            if (c >= O) continue;
            float bb = Bv[c];
            #pragma unroll
            for (int i = 0; i < 8; ++i) {
                int r = m0 + ty * 8 + i;
                float v = acc[i][j] + bb;
                if (POST_RELU) v = fmaxf(v, 0.f);
                size_t yi = (size_t)r * O + c;
                if (YM == 0)   ((float*)Y)[yi] = v;
                else if (f32d) ((float*)Y)[yi] = v;
                else           ((__hip_bfloat16*)Y)[yi] = __float2bfloat16(v);
            }
        }
    }
}

// ---------------- codebook prep --------------------------------------------
__global__ void prep_k(const float* __restrict__ E, float* __restrict__ Et)
{
    int idx = blockIdx.x * 256 + threadIdx.x;   // E is [64][512]
    Et[(idx & 511) * EDIM + (idx >> 9)] = E[idx];
}

__global__ void e2_k(const float* __restrict__ Et, float* __restrict__ e2)
{
    int e = blockIdx.x * 256 + threadIdx.x;
    float s = 0.f;
    #pragma unroll
    for (int d = 0; d < EDIM; ++d) { float v = Et[e * EDIM + d]; s = fmaf(v, v, s); }
    e2[e] = s;
}

// ---------------- VQ as tiled GEMM-argmin ----------------------------------
__global__ __launch_bounds__(256)
void vq_k(float* __restrict__ Zq, const float* __restrict__ Ed,
          const float* __restrict__ Et, const float* __restrict__ e2,
          float* __restrict__ acc)
{
    __shared__ float Zs[64][132];    // [d][row], 128 rows + pad
    __shared__ float Es[64][68];     // [d][code] chunk of 64 codes

    const int tid = threadIdx.x;
    const int tx  = tid & 15;        // code group (4 codes)
    const int ty  = tid >> 4;        // row group (8 rows)
    const int r0  = blockIdx.x * 128;

    // stage Z tile k-major
    #pragma unroll
    for (int it = 0; it < 8; ++it) {
        int idx = tid + it * 256;                // 128 rows x 16 float4
        int dq = idx & 15, m = idx >> 4;
        float4 v = *(const float4*)(Zq + (size_t)(r0 + m) * 64 + dq * 4);
        Zs[dq * 4 + 0][m] = v.x; Zs[dq * 4 + 1][m] = v.y;
        Zs[dq * 4 + 2][m] = v.z; Zs[dq * 4 + 3][m] = v.w;
    }

    float best[8];
    int   bi[8];
    #pragma unroll
    for (int i = 0; i < 8; ++i) { best[i] = 3.4e38f; bi[i] = 0; }

    for (int cc = 0; cc < 8; ++cc) {
        const int c0 = cc * 64;
        #pragma unroll
        for (int it = 0; it < 4; ++it) {
            int idx = tid + it * 256;            // 64 k x 16 float4
            int oq = idx & 15, kk = idx >> 4;
            *(float4*)&Es[kk][oq * 4] =
                *(const float4*)(Ed + (size_t)kk * NEMB + c0 + oq * 4);
        }
        float4 e2v = *(const float4*)(e2 + c0 + tx * 4);
        __syncthreads();

        float a4[8][4] = {};
        #pragma unroll 8
        for (int kk = 0; kk < 64; ++kk) {
            float a[8], b[4];
            *(float4*)&a[0] = *(const float4*)&Zs[kk][ty * 8];
            *(float4*)&a[4] = *(const float4*)&Zs[kk][ty * 8 + 4];
            *(float4*)&b[0] = *(const float4*)&Es[kk][tx * 4];
            #pragma unroll
            for (int i = 0; i < 8; ++i)
                #pragma unroll
                for (int j = 0; j < 4; ++j)
                    a4[i][j] = fmaf(a[i], b[j], a4[i][j]);
        }

        const float e2a[4] = {e2v.x, e2v.y, e2v.z, e2v.w};
        #pragma unroll
        for (int j = 0; j < 4; ++j) {
            const int code = c0 + tx * 4 + j;    // visited in increasing order
            #pragma unroll
            for (int i = 0; i < 8; ++i) {
                float s = fmaf(-2.f, a4[i][j], e2a[j]);
                if (s < best[i]) { best[i] = s; bi[i] = code; }  // strict <: first-min
            }
        }
        __syncthreads();
    }

    // argmin reduce over the 16 lanes sharing each row (tie-break low index)
    #pragma unroll
    for (int i = 0; i < 8; ++i) {
        #pragma unroll
        for (int m = 1; m < 16; m <<= 1) {
            float ob = __shfl_xor(best[i], m);
            int   oi = __shfl_xor(bi[i], m);
            if (ob < best[i] || (ob == best[i] && oi < bi[i])) {
                best[i] = ob; bi[i] = oi;
            }
        }
    }

    // gather winner rows, straight-through write in place, accumulate diff
    float ds = 0.f;
    #pragma unroll
    for (int i = 0; i < 8; ++i) {
        const int row = r0 + ty * 8 + i;
        float4 qv = *(const float4*)(Et + (size_t)bi[i] * 64 + tx * 4);
        float* zp = Zq + (size_t)row * 64 + tx * 4;
        float4 zv = *(const float4*)zp;
        float t;
        t = qv.x - zv.x; ds = fmaf(t, t, ds);
        t = qv.y - zv.y; ds = fmaf(t, t, ds);
        t = qv.z - zv.z; ds = fmaf(t, t, ds);
        t = qv.w - zv.w; ds = fmaf(t, t, ds);
        *(float4*)zp = qv;
    }
    #pragma unroll
    for (int off = 32; off; off >>= 1) ds += __shfl_down(ds, off);
    if ((tid & 63) == 0) atomicAdd(acc, ds);
}

__global__ void diff_k(const float* __restrict__ acc, void* __restrict__ out,
                       size_t off, const int* __restrict__ dtf)
{
    if (threadIdx.x == 0) {
        float v = *acc * (1.0f / 8388608.0f);
        if (*dtf) ((float*)out)[off] = v;
        else      ((__hip_bfloat16*)out)[off] = __float2bfloat16(v);
    }
}

// ---------------------------------------------------------------------------
extern "C" void kernel_launch(void* const* d_in, const int* in_sizes, int n_in,
                              void* d_out, int out_size, void* d_ws, size_t ws_size,
                              hipStream_t stream)
{
    const size_t MB = 1048576;
    char* ws = (char*)d_ws;
    float* Zq  = (float*)ws;                                  // N x 64
    float* A1  = (float*)(ws + 32 * MB);                      // N x 256
    float* A2  = (float*)(ws + 32 * MB + 128 * MB);           // N x 256
    float* Wf  = (float*)(ws + 288 * MB);                     // fp32 weights
    float* Et  = (float*)(ws + 288 * MB + 1310720);           // 512 x 64
    float* e2  = Et + NEMB * EDIM;
    float* acc = e2 + NEMB;
    int*   dtf = (int*)(acc + 1);

    // weight table (K-major transpose for 2-D weights)
    static const int KDIM[32] = {0, 165,0, 128,0, 256,0, 256,0, 32,0, 256,0, 32,0,
                                 256,0, 0, 64,0, 256,0, 32,0, 256,0, 32,0, 256,0, 128,0};
    WTbl t;
    int off[32];
    int cum = 0;
    for (int i = 1; i < 32; ++i) {
        t.p[i - 1]   = d_in[i];
        t.off[i - 1] = cum;
        t.n[i - 1]   = in_sizes[i];
        t.Kd[i - 1]  = KDIM[i];
        off[i] = cum;
        cum += in_sizes[i];
    }
    const float* W_ew0 = Wf + off[1],  *B_ew0 = Wf + off[2];
    const float* W_ew1 = Wf + off[3],  *B_ew1 = Wf + off[4];
    const float* W_ew2 = Wf + off[5],  *B_ew2 = Wf + off[6];
    const float* W_r0a = Wf + off[7],  *B_r0a = Wf + off[8];
    const float* W_r0b = Wf + off[9],  *B_r0b = Wf + off[10];
    const float* W_r1a = Wf + off[11], *B_r1a = Wf + off[12];
    const float* W_r1b = Wf + off[13], *B_r1b = Wf + off[14];
    const float* W_qc  = Wf + off[15], *B_qc  = Wf + off[16];
    const float* Emb   = Wf + off[17];
    const float* W_d0  = Wf + off[18], *B_d0  = Wf + off[19];
    const float* W_s0a = Wf + off[20], *B_s0a = Wf + off[21];
    const float* W_s0b = Wf + off[22], *B_s0b = Wf + off[23];
    const float* W_s1a = Wf + off[24], *B_s1a = Wf + off[25];
    const float* W_s1b = Wf + off[26], *B_s1b = Wf + off[27];
    const float* W_d1  = Wf + off[28], *B_d1  = Wf + off[29];
    const float* W_d2  = Wf + off[30], *B_d2  = Wf + off[31];

    dim3 blk(256);
    const int NB = NTOT / 64;          // 2048 row blocks for fused kernels
    auto g = [](int o) { return dim3((o + 63) / 64, NTOT / 128); };  // swizzled

    detect_k<<<1, blk, 0, stream>>>(d_in[0], dtf, acc);
    convw_k<<<31, blk, 0, stream>>>(t, Wf, dtf);
    prep_k<<<128, blk, 0, stream>>>(Emb, Et);
    e2_k<<<2, blk, 0, stream>>>(Et, e2);

    // ---- encoder ----
    enc01_k<<<NB, blk, 0, stream>>>(d_in[0], W_ew0, B_ew0, W_ew1, B_ew1, A1, dtf);
    gemm_k<false, false, 0><<<g(256), blk, 0, stream>>>(A1, W_ew2, B_ew2, A2, 256, 256, dtf);
    res_k<<<NB, blk, 0, stream>>>(A2, W_r0a, B_r0a, W_r0b, B_r0b);
    res_k<<<NB, blk, 0, stream>>>(A2, W_r1a, B_r1a, W_r1b, B_r1b);
    gemm_k<true, false, 0><<<g(64), blk, 0, stream>>>(A2, W_qc, B_qc, Zq, 256, 64, dtf);

    // ---- VQ (in place, GEMM-argmin) ----
    vq_k<<<NTOT / 128, blk, 0, stream>>>(Zq, Emb, Et, e2, acc);

    // ---- decoder ----
    gemm_k<false, false, 0><<<g(256), blk, 0, stream>>>(Zq, W_d0, B_d0, A1, 64, 256, dtf);
    res_k<<<NB, blk, 0, stream>>>(A1, W_s0a, B_s0a, W_s0b, B_s0b);
    res_k<<<NB, blk, 0, stream>>>(A1, W_s1a, B_s1a, W_s1b, B_s1b);
    gemm_k<true, true, 0><<<g(128), blk, 0, stream>>>(A1, W_d1, B_d1, A2, 256, 128, dtf);
    gemm_k<false, false, 1><<<g(165), blk, 0, stream>>>(A2, W_d2, B_d2, d_out, 128, 165, dtf);

    diff_k<<<1, 64, 0, stream>>>(acc, d_out, (size_t)NTOT * 165, dtf);
}